// Round 7
// baseline (625.670 us; speedup 1.0000x reference)
//
#include <hip/hip_runtime.h>

#define N_NODES 50000
#define N_EDGES 1600000
#define IN_CH 128
#define HEADS 4
#define HC 64                      // HEADS*OUT_CH
#define E_FULL (N_EDGES + N_NODES)
#define NEG_SLOPE 0.2f

#define BUCKET_NODES 98
#define NBUCK 512                  // 512*98 = 50176 >= 50000
#define BIN_TILE 2048              // edges per bin block (256 thr x 8)
#define NBLK_BIN ((N_EDGES + BIN_TILE - 1) / BIN_TILE)   // 782
#define T_FLAT (NBUCK * NBLK_BIN)                        // 400384
#define SCANA_BLOCKS (T_FLAT / 256)                      // 1564 (exact)

__device__ __forceinline__ float leaky(float s) { return s >= 0.f ? s : NEG_SLOPE * s; }

__device__ __forceinline__ unsigned f2bf(float f) {  // round-to-nearest-even
    unsigned u = __float_as_uint(f);
    return (u + 0x7fffu + ((u >> 16) & 1u)) >> 16;
}
__device__ __forceinline__ float bf2f(unsigned v) {
    return __uint_as_float(v << 16);
}

// ---------------- Kernel A: h = x @ W (bf16 out), fused attention scalars --
__global__ __launch_bounds__(256) void gemm_h_kernel(
    const float* __restrict__ x, const float* __restrict__ weight,
    const float* __restrict__ att, unsigned short* __restrict__ h16,
    float* __restrict__ s_src, float* __restrict__ s_dst)
{
    __shared__ float w_lds[IN_CH * HC];   // 32 KB
    __shared__ float x_lds[8 * IN_CH];    // 4 KB
    const int tid = threadIdx.x;
    const int nbase = blockIdx.x * 8;

    for (int i = tid; i < IN_CH * HC; i += 256) w_lds[i] = weight[i];
    for (int i = tid; i < 8 * IN_CH; i += 256) {
        int n = nbase + i / IN_CH;
        x_lds[i] = (n < N_NODES) ? x[(size_t)n * IN_CH + (i % IN_CH)] : 0.f;
    }
    __syncthreads();

    const int w = tid >> 6;
    const int lane = tid & 63;
    const int n0 = nbase + w;
    const int n1 = nbase + 4 + w;

    float acc0 = 0.f, acc1 = 0.f;
    #pragma unroll 8
    for (int k = 0; k < IN_CH; ++k) {
        float wv = w_lds[k * HC + lane];
        acc0 = fmaf(x_lds[w * IN_CH + k], wv, acc0);
        acc1 = fmaf(x_lds[(w + 4) * IN_CH + k], wv, acc1);
    }

    if (n0 < N_NODES) h16[(size_t)n0 * HC + lane] = (unsigned short)f2bf(acc0);
    if (n1 < N_NODES) h16[(size_t)n1 * HC + lane] = (unsigned short)f2bf(acc1);

    const int hd = lane >> 4, c = lane & 15;
    float as = att[hd * 32 + c], ad = att[hd * 32 + 16 + c];
    float ts0 = acc0 * as, td0 = acc0 * ad;
    float ts1 = acc1 * as, td1 = acc1 * ad;
    #pragma unroll
    for (int m = 8; m >= 1; m >>= 1) {
        ts0 += __shfl_xor(ts0, m, 64);
        td0 += __shfl_xor(td0, m, 64);
        ts1 += __shfl_xor(ts1, m, 64);
        td1 += __shfl_xor(td1, m, 64);
    }
    if (c == 0) {
        if (n0 < N_NODES) { s_src[n0 * HEADS + hd] = ts0; s_dst[n0 * HEADS + hd] = td0; }
        if (n1 < N_NODES) { s_src[n1 * HEADS + hd] = ts1; s_dst[n1 * HEADS + hd] = td1; }
    }
}

// ---------------- Kernel H: per-(block,bucket) histogram (no atomics) -----
__global__ __launch_bounds__(256) void histM_kernel(
    const int* __restrict__ ei, unsigned* __restrict__ M)
{
    __shared__ unsigned lh[NBUCK];
    const int tid = threadIdx.x;
    for (int j = tid; j < NBUCK; j += 256) lh[j] = 0;
    __syncthreads();
    const int base = blockIdx.x * BIN_TILE;
    #pragma unroll
    for (int k = 0; k < 8; ++k) {
        int e = base + k * 256 + tid;
        if (e < N_EDGES) {
            unsigned r = (unsigned)ei[e];
            atomicAdd(&lh[r / BUCKET_NODES], 1u);
        }
    }
    __syncthreads();
    unsigned* Mb = M + (size_t)blockIdx.x * NBUCK;
    for (int j = tid; j < NBUCK; j += 256) Mb[j] = lh[j];
}

// ---------------- Scan over flattened [bucket][block] counts ---------------
__device__ __forceinline__ unsigned block_excl_scan(unsigned v, unsigned* total,
                                                    int tid) {
    const int lane = tid & 63, wid = tid >> 6;
    unsigned x = v;
    #pragma unroll
    for (int d = 1; d < 64; d <<= 1) {
        unsigned t = __shfl_up(x, d, 64);
        if (lane >= d) x += t;
    }
    __shared__ unsigned wsum[4];
    if (lane == 63) wsum[wid] = x;
    __syncthreads();
    unsigned woff = 0;
    for (int i = 0; i < wid; ++i) woff += wsum[i];
    unsigned incl = x + woff;
    if (tid == 255) *total = incl;
    return incl - v;
}

__global__ __launch_bounds__(256) void scanA_kernel(
    const unsigned* __restrict__ M, unsigned* __restrict__ localx,
    unsigned* __restrict__ partials)
{
    const int tid = threadIdx.x;
    const int f = blockIdx.x * 256 + tid;   // flat = bucket*NBLK_BIN + block
    unsigned v = 0;
    if (f < T_FLAT) {
        int bucket = f / NBLK_BIN;
        int blk = f - bucket * NBLK_BIN;
        v = M[(size_t)blk * NBUCK + bucket];
    }
    __shared__ unsigned tot;
    unsigned excl = block_excl_scan(v, &tot, tid);
    if (f < T_FLAT) localx[f] = excl;
    __syncthreads();
    if (tid == 0) partials[blockIdx.x] = tot;
}

__global__ __launch_bounds__(256) void scanB_kernel(
    const unsigned* __restrict__ partials, unsigned* __restrict__ pscan)
{
    __shared__ unsigned tot_sh;
    __shared__ unsigned carry_sh;
    const int tid = threadIdx.x;
    if (tid == 0) carry_sh = 0;
    __syncthreads();
    const int nchunk = (SCANA_BLOCKS + 255) / 256;
    for (int ch = 0; ch < nchunk; ++ch) {
        int i = ch * 256 + tid;
        unsigned v = (i < SCANA_BLOCKS) ? partials[i] : 0u;
        unsigned excl = block_excl_scan(v, &tot_sh, tid);
        unsigned carry = carry_sh;
        if (i < SCANA_BLOCKS) pscan[i] = excl + carry;
        __syncthreads();
        if (tid == 0) carry_sh += tot_sh;
        __syncthreads();
    }
}

__global__ __launch_bounds__(256) void scanC_kernel(
    const unsigned* __restrict__ localx, const unsigned* __restrict__ pscan,
    unsigned* __restrict__ S)
{
    const int f = blockIdx.x * 256 + threadIdx.x;
    if (f < T_FLAT) S[f] = localx[f] + pscan[blockIdx.x];
    if (f == 0) S[T_FLAT] = N_EDGES;
}

// ---------------- Kernel D: bin pass — alpha/eif + grouped slot writes ----
__global__ __launch_bounds__(256) void bin_kernel(
    const int* __restrict__ ei, const float* __restrict__ ea,
    const float* __restrict__ s_src, const float* __restrict__ s_dst,
    const unsigned* __restrict__ S, uint4* __restrict__ slots,
    float* __restrict__ alpha, float* __restrict__ eif)
{
    __shared__ unsigned lh[NBUCK];
    __shared__ unsigned lbase[NBUCK];
    const int tid = threadIdx.x;
    for (int j = tid; j < NBUCK; j += 256) lh[j] = 0;
    __syncthreads();

    const int base = blockIdx.x * BIN_TILE;
    unsigned b8[8], idx8[8], p0[8], p1[8], p2[8];
    #pragma unroll
    for (int k = 0; k < 8; ++k) {
        int e = base + k * 256 + tid;
        b8[k] = 0xffffffffu;
        if (e < N_EDGES) {
            unsigned r = (unsigned)ei[e];
            unsigned c = (unsigned)ei[N_EDGES + e];
            float4 ss = ((const float4*)s_src)[r];
            float4 sd = ((const float4*)s_dst)[c];
            float4 eav = ((const float4*)ea)[e];
            float4 a;
            a.x = leaky(ss.x + sd.x) * eav.x;
            a.y = leaky(ss.y + sd.y) * eav.y;
            a.z = leaky(ss.z + sd.z) * eav.z;
            a.w = leaky(ss.w + sd.w) * eav.w;
            ((float4*)alpha)[e] = a;
            eif[e] = (float)r;
            eif[(size_t)E_FULL + e] = (float)c;

            unsigned bk = r / BUCKET_NODES;
            unsigned rl = r - bk * BUCKET_NODES;
            b8[k] = bk;
            p0[k] = c | (rl << 16);
            p1[k] = f2bf(a.x) | (f2bf(a.y) << 16);
            p2[k] = f2bf(a.z) | (f2bf(a.w) << 16);
            idx8[k] = atomicAdd(&lh[bk], 1u);
        }
    }
    __syncthreads();
    for (int j = tid; j < NBUCK; j += 256)
        lbase[j] = S[(size_t)j * NBLK_BIN + blockIdx.x];
    __syncthreads();
    #pragma unroll
    for (int k = 0; k < 8; ++k) {
        if (b8[k] != 0xffffffffu)
            slots[lbase[b8[k]] + idx8[k]] = make_uint4(p0[k], p1[k], p2[k], 0u);
    }
}

// ---------------- Kernel E: bucket gather with LDS f32 accumulator --------
__device__ __forceinline__ float slot_alpha(uint4 s, int hd) {
    unsigned w = (hd & 2) ? s.z : s.y;
    return bf2f((hd & 1) ? (w >> 16) : (w & 0xffffu));
}

__global__ __launch_bounds__(512) void gather_kernel(
    const unsigned short* __restrict__ h16, const float* __restrict__ s_src,
    const float* __restrict__ s_dst, const float* __restrict__ bias,
    const unsigned* __restrict__ S, const uint4* __restrict__ slots,
    float* __restrict__ alpha, float* __restrict__ out, float* __restrict__ eif)
{
    __shared__ float acc[BUCKET_NODES * HC];   // 25088 B
    const int tid = threadIdx.x;
    const int b = blockIdx.x;
    const int nstart = b * BUCKET_NODES;
    int nn = N_NODES - nstart;
    if (nn > BUCKET_NODES) nn = BUCKET_NODES;
    if (nn < 0) nn = 0;

    for (int j = tid; j < nn * HC; j += 512) acc[j] = 0.f;
    __syncthreads();

    const unsigned start = S[(size_t)b * NBLK_BIN];
    const unsigned end   = S[(size_t)(b + 1) * NBLK_BIN];
    const int wid = tid >> 6, lane = tid & 63, hd = lane >> 4;

    const unsigned cnt = end - start;
    const unsigned chunk = (cnt + 7) >> 3;
    unsigned i = start + wid * chunk;
    unsigned we = i + chunk;
    if (we > end) we = end;

    for (; i + 4 <= we; i += 4) {
        uint4 s0 = slots[i];
        uint4 s1 = slots[i + 1];
        uint4 s2 = slots[i + 2];
        uint4 s3 = slots[i + 3];
        float h0 = bf2f(h16[(size_t)(s0.x & 0xffffu) * HC + lane]);
        float h1 = bf2f(h16[(size_t)(s1.x & 0xffffu) * HC + lane]);
        float h2 = bf2f(h16[(size_t)(s2.x & 0xffffu) * HC + lane]);
        float h3 = bf2f(h16[(size_t)(s3.x & 0xffffu) * HC + lane]);
        atomicAdd(&acc[(s0.x >> 16) * HC + lane], slot_alpha(s0, hd) * h0);
        atomicAdd(&acc[(s1.x >> 16) * HC + lane], slot_alpha(s1, hd) * h1);
        atomicAdd(&acc[(s2.x >> 16) * HC + lane], slot_alpha(s2, hd) * h2);
        atomicAdd(&acc[(s3.x >> 16) * HC + lane], slot_alpha(s3, hd) * h3);
    }
    for (; i < we; ++i) {
        uint4 s0 = slots[i];
        float h0 = bf2f(h16[(size_t)(s0.x & 0xffffu) * HC + lane]);
        atomicAdd(&acc[(s0.x >> 16) * HC + lane], slot_alpha(s0, hd) * h0);
    }
    __syncthreads();

    // writeback: out = acc + bias + self-loop message
    for (int j = tid; j < nn * HC; j += 512) {
        int n = nstart + (j >> 6);
        int ch = j & 63, hdj = ch >> 4;
        float ssum = s_src[n * HEADS + hdj] + s_dst[n * HEADS + hdj];
        out[(size_t)n * HC + ch] =
            acc[j] + bias[ch] + leaky(ssum) * bf2f(h16[(size_t)n * HC + ch]);
    }
    // tails: self-loop alpha + edge_index_full loop entries
    for (int j = tid; j < nn * HEADS; j += 512) {
        int n = nstart + (j >> 2);
        int hdj = j & 3;
        float ssum = s_src[n * HEADS + hdj] + s_dst[n * HEADS + hdj];
        alpha[(size_t)(N_EDGES + n) * HEADS + hdj] = leaky(ssum);
    }
    for (int j = tid; j < nn; j += 512) {
        int n = nstart + j;
        eif[N_EDGES + n] = (float)n;
        eif[(size_t)E_FULL + N_EDGES + n] = (float)n;
    }
}

extern "C" void kernel_launch(void* const* d_in, const int* in_sizes, int n_in,
                              void* d_out, int out_size, void* d_ws, size_t ws_size,
                              hipStream_t stream) {
    const float* x      = (const float*)d_in[0];
    const int*   ei     = (const int*)  d_in[1];
    const float* ea     = (const float*)d_in[2];
    const float* weight = (const float*)d_in[3];
    const float* att    = (const float*)d_in[4];
    const float* bias   = (const float*)d_in[5];

    float* out   = (float*)d_out;                    // N_NODES*HC
    float* eif   = out + (size_t)N_NODES * HC;       // 2*E_FULL (as float)
    float* alpha = eif + (size_t)2 * E_FULL;         // E_FULL*HEADS

    // workspace layout (slots first for 16B alignment)
    uint4* slots = (uint4*)d_ws;                                   // 25.6 MB
    unsigned short* h16 = (unsigned short*)(slots + (size_t)N_EDGES);  // 6.4 MB
    float* s_src = (float*)(h16 + (size_t)N_NODES * HC);           // 0.8 MB
    float* s_dst = s_src + (size_t)N_NODES * HEADS;                // 0.8 MB
    unsigned* M        = (unsigned*)(s_dst + (size_t)N_NODES * HEADS); // 1.6 MB
    unsigned* localx   = M + (size_t)NBLK_BIN * NBUCK;             // 1.6 MB
    unsigned* partials = localx + T_FLAT;                          // 6 KB
    unsigned* pscan    = partials + SCANA_BLOCKS;                  // 6 KB
    unsigned* S        = pscan + SCANA_BLOCKS;                     // 1.6 MB (T_FLAT+1)

    gemm_h_kernel<<<(N_NODES + 7) / 8, 256, 0, stream>>>(x, weight, att, h16, s_src, s_dst);
    histM_kernel<<<NBLK_BIN, 256, 0, stream>>>(ei, M);
    scanA_kernel<<<SCANA_BLOCKS, 256, 0, stream>>>(M, localx, partials);
    scanB_kernel<<<1, 256, 0, stream>>>(partials, pscan);
    scanC_kernel<<<SCANA_BLOCKS, 256, 0, stream>>>(localx, pscan, S);
    bin_kernel<<<NBLK_BIN, 256, 0, stream>>>(ei, ea, s_src, s_dst, S, slots, alpha, eif);
    gather_kernel<<<NBUCK, 512, 0, stream>>>(h16, s_src, s_dst, bias, S, slots, alpha, out, eif);
}

// Round 8
// 183.072 us; speedup vs baseline: 3.4176x; 3.4176x over previous
//
#include <hip/hip_runtime.h>

#define N_NODES 50000
#define N_EDGES 1600000
#define IN_CH 128
#define HEADS 4
#define HC 64                      // HEADS*OUT_CH
#define E_FULL (N_EDGES + N_NODES)
#define NEG_SLOPE 0.2f

#define BUCKET_NODES 98
#define NBUCK 512                  // 512*98 = 50176 >= 50000
#define BIN_TILE 2048              // edges per bin block (256 thr x 8)
#define NBLK_BIN ((N_EDGES + BIN_TILE - 1) / BIN_TILE)   // 782
#define T_FLAT (NBUCK * NBLK_BIN)                        // 400384
#define SCANA_BLOCKS (T_FLAT / 256)                      // 1564 (exact)

__device__ __forceinline__ float leaky(float s) { return s >= 0.f ? s : NEG_SLOPE * s; }

__device__ __forceinline__ unsigned f2bf(float f) {  // round-to-nearest-even
    unsigned u = __float_as_uint(f);
    return (u + 0x7fffu + ((u >> 16) & 1u)) >> 16;
}
__device__ __forceinline__ float bf2f(unsigned v) {
    return __uint_as_float(v << 16);
}

// ---------------- Kernel A: h = x @ W (bf16 out), fused attention scalars --
__global__ __launch_bounds__(256) void gemm_h_kernel(
    const float* __restrict__ x, const float* __restrict__ weight,
    const float* __restrict__ att, unsigned short* __restrict__ h16,
    float* __restrict__ s_src, float* __restrict__ s_dst)
{
    __shared__ float w_lds[IN_CH * HC];   // 32 KB
    __shared__ float x_lds[8 * IN_CH];    // 4 KB
    const int tid = threadIdx.x;
    const int nbase = blockIdx.x * 8;

    for (int i = tid; i < IN_CH * HC; i += 256) w_lds[i] = weight[i];
    for (int i = tid; i < 8 * IN_CH; i += 256) {
        int n = nbase + i / IN_CH;
        x_lds[i] = (n < N_NODES) ? x[(size_t)n * IN_CH + (i % IN_CH)] : 0.f;
    }
    __syncthreads();

    const int w = tid >> 6;
    const int lane = tid & 63;
    const int n0 = nbase + w;
    const int n1 = nbase + 4 + w;

    float acc0 = 0.f, acc1 = 0.f;
    #pragma unroll 8
    for (int k = 0; k < IN_CH; ++k) {
        float wv = w_lds[k * HC + lane];
        acc0 = fmaf(x_lds[w * IN_CH + k], wv, acc0);
        acc1 = fmaf(x_lds[(w + 4) * IN_CH + k], wv, acc1);
    }

    if (n0 < N_NODES) h16[(size_t)n0 * HC + lane] = (unsigned short)f2bf(acc0);
    if (n1 < N_NODES) h16[(size_t)n1 * HC + lane] = (unsigned short)f2bf(acc1);

    const int hd = lane >> 4, c = lane & 15;
    float as = att[hd * 32 + c], ad = att[hd * 32 + 16 + c];
    float ts0 = acc0 * as, td0 = acc0 * ad;
    float ts1 = acc1 * as, td1 = acc1 * ad;
    #pragma unroll
    for (int m = 8; m >= 1; m >>= 1) {
        ts0 += __shfl_xor(ts0, m, 64);
        td0 += __shfl_xor(td0, m, 64);
        ts1 += __shfl_xor(ts1, m, 64);
        td1 += __shfl_xor(td1, m, 64);
    }
    if (c == 0) {
        if (n0 < N_NODES) { s_src[n0 * HEADS + hd] = ts0; s_dst[n0 * HEADS + hd] = td0; }
        if (n1 < N_NODES) { s_src[n1 * HEADS + hd] = ts1; s_dst[n1 * HEADS + hd] = td1; }
    }
}

// ---------------- Kernel H: per-(block,bucket) histogram + eif ------------
__global__ __launch_bounds__(256) void histM_kernel(
    const int* __restrict__ ei, unsigned* __restrict__ M,
    float* __restrict__ eif)
{
    __shared__ unsigned lh[NBUCK];
    const int tid = threadIdx.x;
    for (int j = tid; j < NBUCK; j += 256) lh[j] = 0;
    __syncthreads();
    const int base = blockIdx.x * BIN_TILE;
    #pragma unroll
    for (int k = 0; k < 8; ++k) {
        int e = base + k * 256 + tid;
        if (e < N_EDGES) {
            unsigned r = (unsigned)ei[e];
            unsigned c = (unsigned)ei[N_EDGES + e];
            eif[e] = (float)r;
            eif[(size_t)E_FULL + e] = (float)c;
            atomicAdd(&lh[r / BUCKET_NODES], 1u);
        }
    }
    __syncthreads();
    unsigned* Mb = M + (size_t)blockIdx.x * NBUCK;
    for (int j = tid; j < NBUCK; j += 256) Mb[j] = lh[j];
}

// ---------------- Scan over flattened [bucket][block] counts ---------------
__device__ __forceinline__ unsigned block_excl_scan(unsigned v, unsigned* total,
                                                    int tid) {
    const int lane = tid & 63, wid = tid >> 6;
    unsigned x = v;
    #pragma unroll
    for (int d = 1; d < 64; d <<= 1) {
        unsigned t = __shfl_up(x, d, 64);
        if (lane >= d) x += t;
    }
    __shared__ unsigned wsum[4];
    if (lane == 63) wsum[wid] = x;
    __syncthreads();
    unsigned woff = 0;
    for (int i = 0; i < wid; ++i) woff += wsum[i];
    unsigned incl = x + woff;
    if (tid == 255) *total = incl;
    return incl - v;
}

__global__ __launch_bounds__(256) void scanA_kernel(
    const unsigned* __restrict__ M, unsigned* __restrict__ localx,
    unsigned* __restrict__ partials)
{
    const int tid = threadIdx.x;
    const int f = blockIdx.x * 256 + tid;   // flat = bucket*NBLK_BIN + block
    unsigned v = 0;
    if (f < T_FLAT) {
        int bucket = f / NBLK_BIN;
        int blk = f - bucket * NBLK_BIN;
        v = M[(size_t)blk * NBUCK + bucket];
    }
    __shared__ unsigned tot;
    unsigned excl = block_excl_scan(v, &tot, tid);
    if (f < T_FLAT) localx[f] = excl;
    __syncthreads();
    if (tid == 0) partials[blockIdx.x] = tot;
}

__global__ __launch_bounds__(256) void scanB_kernel(
    const unsigned* __restrict__ partials, unsigned* __restrict__ pscan)
{
    __shared__ unsigned tot_sh;
    __shared__ unsigned carry_sh;
    const int tid = threadIdx.x;
    if (tid == 0) carry_sh = 0;
    __syncthreads();
    const int nchunk = (SCANA_BLOCKS + 255) / 256;
    for (int ch = 0; ch < nchunk; ++ch) {
        int i = ch * 256 + tid;
        unsigned v = (i < SCANA_BLOCKS) ? partials[i] : 0u;
        unsigned excl = block_excl_scan(v, &tot_sh, tid);
        unsigned carry = carry_sh;
        if (i < SCANA_BLOCKS) pscan[i] = excl + carry;
        __syncthreads();
        if (tid == 0) carry_sh += tot_sh;
        __syncthreads();
    }
}

__global__ __launch_bounds__(256) void scanC_kernel(
    const unsigned* __restrict__ localx, const unsigned* __restrict__ pscan,
    unsigned* __restrict__ S)
{
    const int f = blockIdx.x * 256 + threadIdx.x;
    if (f < T_FLAT) S[f] = localx[f] + pscan[blockIdx.x];
    if (f == 0) S[T_FLAT] = N_EDGES;
}

// ---------------- Kernel D: bin pass — alpha + grouped slot writes --------
__global__ __launch_bounds__(256) void bin_kernel(
    const int* __restrict__ ei, const float* __restrict__ ea,
    const float* __restrict__ s_src, const float* __restrict__ s_dst,
    const unsigned* __restrict__ S, uint4* __restrict__ slots,
    float* __restrict__ alpha)
{
    __shared__ unsigned lh[NBUCK];
    __shared__ unsigned lbase[NBUCK];
    const int tid = threadIdx.x;
    for (int j = tid; j < NBUCK; j += 256) lh[j] = 0;
    __syncthreads();

    const int base = blockIdx.x * BIN_TILE;
    unsigned b8[8], idx8[8], p0[8], p1[8], p2[8];
    #pragma unroll
    for (int k = 0; k < 8; ++k) {
        int e = base + k * 256 + tid;
        b8[k] = 0xffffffffu;
        if (e < N_EDGES) {
            unsigned r = (unsigned)ei[e];
            unsigned c = (unsigned)ei[N_EDGES + e];
            float4 ss = ((const float4*)s_src)[r];
            float4 sd = ((const float4*)s_dst)[c];
            float4 eav = ((const float4*)ea)[e];
            float4 a;
            a.x = leaky(ss.x + sd.x) * eav.x;
            a.y = leaky(ss.y + sd.y) * eav.y;
            a.z = leaky(ss.z + sd.z) * eav.z;
            a.w = leaky(ss.w + sd.w) * eav.w;
            ((float4*)alpha)[e] = a;

            unsigned bk = r / BUCKET_NODES;
            unsigned rl = r - bk * BUCKET_NODES;
            b8[k] = bk;
            p0[k] = c | (rl << 16);
            p1[k] = f2bf(a.x) | (f2bf(a.y) << 16);
            p2[k] = f2bf(a.z) | (f2bf(a.w) << 16);
            idx8[k] = atomicAdd(&lh[bk], 1u);
        }
    }
    __syncthreads();
    for (int j = tid; j < NBUCK; j += 256)
        lbase[j] = S[(size_t)j * NBLK_BIN + blockIdx.x];
    __syncthreads();
    #pragma unroll
    for (int k = 0; k < 8; ++k) {
        if (b8[k] != 0xffffffffu)
            slots[lbase[b8[k]] + idx8[k]] = make_uint4(p0[k], p1[k], p2[k], 0u);
    }
}

// ---------------- Kernel S: per-bucket counting sort -> node-sorted slots --
__global__ __launch_bounds__(256) void sort_kernel(
    const unsigned* __restrict__ S, const uint4* __restrict__ slots,
    uint4* __restrict__ slots2, unsigned* __restrict__ offs)
{
    __shared__ unsigned cnt[BUCKET_NODES];
    __shared__ unsigned cur[BUCKET_NODES];
    const int b = blockIdx.x;
    const int tid = threadIdx.x;
    const unsigned start = S[(size_t)b * NBLK_BIN];
    const unsigned end   = S[(size_t)(b + 1) * NBLK_BIN];

    for (int j = tid; j < BUCKET_NODES; j += 256) cnt[j] = 0;
    __syncthreads();
    for (unsigned i = start + tid; i < end; i += 256)
        atomicAdd(&cnt[slots[i].x >> 16], 1u);
    __syncthreads();
    if (tid == 0) {
        unsigned run = 0;
        for (int j = 0; j < BUCKET_NODES; ++j) {
            unsigned c = cnt[j];
            cur[j] = run;
            run += c;
        }
    }
    __syncthreads();
    const int nstart = b * BUCKET_NODES;
    for (int j = tid; j < BUCKET_NODES; j += 256) {
        int n = nstart + j;
        if (n <= N_NODES) offs[n] = start + cur[j];
    }
    __syncthreads();
    for (unsigned i = start + tid; i < end; i += 256) {
        uint4 s = slots[i];
        unsigned rl = s.x >> 16;
        unsigned pos = start + atomicAdd(&cur[rl], 1u);
        slots2[pos] = s;
    }
}

// ---------------- Kernel E: per-node register gather ----------------------
__device__ __forceinline__ float slot_alpha(uint4 s, int hd) {
    unsigned w = (hd & 2) ? s.z : s.y;
    return bf2f((hd & 1) ? (w >> 16) : (w & 0xffffu));
}

__global__ __launch_bounds__(256) void gather_kernel(
    const unsigned short* __restrict__ h16, const float* __restrict__ s_src,
    const float* __restrict__ s_dst, const float* __restrict__ bias,
    const unsigned* __restrict__ offs, const uint4* __restrict__ slots2,
    float* __restrict__ alpha, float* __restrict__ out, float* __restrict__ eif)
{
    const int tid = threadIdx.x;
    const int n = blockIdx.x * 4 + (tid >> 6);
    if (n >= N_NODES) return;
    const int lane = tid & 63, hd = lane >> 4;

    // self-loop contribution (ea = 1) + bias
    float s_self = s_src[n * HEADS + hd] + s_dst[n * HEADS + hd];
    float acc = bias[lane] + leaky(s_self) * bf2f(h16[(size_t)n * HC + lane]);

    const unsigned start = offs[n];
    const int cnt = (int)(offs[n + 1] - start);

    int i = 0;
    for (; i + 3 < cnt; i += 4) {
        uint4 s0 = slots2[start + i];
        uint4 s1 = slots2[start + i + 1];
        uint4 s2 = slots2[start + i + 2];
        uint4 s3 = slots2[start + i + 3];
        float h0 = bf2f(h16[(size_t)(s0.x & 0xffffu) * HC + lane]);
        float h1 = bf2f(h16[(size_t)(s1.x & 0xffffu) * HC + lane]);
        float h2 = bf2f(h16[(size_t)(s2.x & 0xffffu) * HC + lane]);
        float h3 = bf2f(h16[(size_t)(s3.x & 0xffffu) * HC + lane]);
        acc = fmaf(slot_alpha(s0, hd), h0, acc);
        acc = fmaf(slot_alpha(s1, hd), h1, acc);
        acc = fmaf(slot_alpha(s2, hd), h2, acc);
        acc = fmaf(slot_alpha(s3, hd), h3, acc);
    }
    for (; i < cnt; ++i) {
        uint4 s0 = slots2[start + i];
        float h0 = bf2f(h16[(size_t)(s0.x & 0xffffu) * HC + lane]);
        acc = fmaf(slot_alpha(s0, hd), h0, acc);
    }
    out[(size_t)n * HC + lane] = acc;

    // tails: self-loop alpha + edge_index_full loop entries
    if (lane < HEADS) {
        float s2 = s_src[n * HEADS + lane] + s_dst[n * HEADS + lane];
        alpha[(size_t)(N_EDGES + n) * HEADS + lane] = leaky(s2);
    }
    if (lane == 4) eif[N_EDGES + n] = (float)n;
    if (lane == 5) eif[(size_t)E_FULL + N_EDGES + n] = (float)n;
}

extern "C" void kernel_launch(void* const* d_in, const int* in_sizes, int n_in,
                              void* d_out, int out_size, void* d_ws, size_t ws_size,
                              hipStream_t stream) {
    const float* x      = (const float*)d_in[0];
    const int*   ei     = (const int*)  d_in[1];
    const float* ea     = (const float*)d_in[2];
    const float* weight = (const float*)d_in[3];
    const float* att    = (const float*)d_in[4];
    const float* bias   = (const float*)d_in[5];

    float* out   = (float*)d_out;                    // N_NODES*HC
    float* eif   = out + (size_t)N_NODES * HC;       // 2*E_FULL (as float)
    float* alpha = eif + (size_t)2 * E_FULL;         // E_FULL*HEADS

    // workspace layout (uint4 arrays first for 16B alignment); ~64.2 MB total
    uint4* slots  = (uint4*)d_ws;                                      // 25.6 MB
    uint4* slots2 = slots + (size_t)N_EDGES;                           // 25.6 MB
    unsigned short* h16 = (unsigned short*)(slots2 + (size_t)N_EDGES); // 6.4 MB
    float* s_src = (float*)(h16 + (size_t)N_NODES * HC);               // 0.8 MB
    float* s_dst = s_src + (size_t)N_NODES * HEADS;                    // 0.8 MB
    unsigned* M        = (unsigned*)(s_dst + (size_t)N_NODES * HEADS); // 1.6 MB
    unsigned* localx   = M + (size_t)NBLK_BIN * NBUCK;                 // 1.6 MB
    unsigned* partials = localx + T_FLAT;                              // 6 KB
    unsigned* pscan    = partials + SCANA_BLOCKS;                      // 6 KB
    unsigned* S        = pscan + SCANA_BLOCKS;                         // 1.6 MB (T_FLAT+1)
    unsigned* offs     = S + (T_FLAT + 1);                             // 0.2 MB (N_NODES+1)

    gemm_h_kernel<<<(N_NODES + 7) / 8, 256, 0, stream>>>(x, weight, att, h16, s_src, s_dst);
    histM_kernel<<<NBLK_BIN, 256, 0, stream>>>(ei, M, eif);
    scanA_kernel<<<SCANA_BLOCKS, 256, 0, stream>>>(M, localx, partials);
    scanB_kernel<<<1, 256, 0, stream>>>(partials, pscan);
    scanC_kernel<<<SCANA_BLOCKS, 256, 0, stream>>>(localx, pscan, S);
    bin_kernel<<<NBLK_BIN, 256, 0, stream>>>(ei, ea, s_src, s_dst, S, slots, alpha);
    sort_kernel<<<NBUCK, 256, 0, stream>>>(S, slots, slots2, offs);
    gather_kernel<<<(N_NODES + 3) / 4, 256, 0, stream>>>(
        h16, s_src, s_dst, bias, offs, slots2, alpha, out, eif);
}

// Round 9
// 167.469 us; speedup vs baseline: 3.7360x; 1.0932x over previous
//
#include <hip/hip_runtime.h>

#define N_NODES 50000
#define N_EDGES 1600000
#define IN_CH 128
#define HEADS 4
#define HC 64                      // HEADS*OUT_CH
#define E_FULL (N_EDGES + N_NODES)
#define NEG_SLOPE 0.2f

#define BUCKET_NODES 98
#define NBUCK 512                  // 512*98 = 50176 >= 50000
#define BIN_TILE 2048              // edges per bin block (256 thr x 8)
#define NBLK_BIN ((N_EDGES + BIN_TILE - 1) / BIN_TILE)   // 782
#define T_FLAT (NBUCK * NBLK_BIN)                        // 400384
#define SCANA_BLOCKS (T_FLAT / 256)                      // 1564 (exact)

typedef __attribute__((ext_vector_type(8))) short short8v;
typedef __attribute__((ext_vector_type(4))) float float4v;

__device__ __forceinline__ float leaky(float s) { return s >= 0.f ? s : NEG_SLOPE * s; }

__device__ __forceinline__ unsigned f2bf(float f) {  // round-to-nearest-even
    unsigned u = __float_as_uint(f);
    return (u + 0x7fffu + ((u >> 16) & 1u)) >> 16;
}
__device__ __forceinline__ float bf2f(unsigned v) {
    return __uint_as_float(v << 16);
}

// ---------------- Kernel W: weight f32[128][64] -> bf16 wT[64][128] -------
__global__ __launch_bounds__(256) void wcvt_kernel(
    const float* __restrict__ w, unsigned short* __restrict__ wT)
{
    int i = blockIdx.x * 256 + threadIdx.x;
    if (i < IN_CH * HC) {
        int k = i >> 6, c = i & 63;
        wT[c * IN_CH + k] = (unsigned short)f2bf(w[i]);
    }
}

// ---------------- Kernel A: h = x @ W via MFMA, fused attention scalars ----
// Block: 256 thr = 4 waves, 64 nodes. Wave w: row-tile rt=w (16 nodes).
// LDS x-tile bf16 [64][128], 16B-chunk XOR swizzle (chunk ^ (row&7)).
__global__ __launch_bounds__(256) void gemm_h_kernel(
    const float* __restrict__ x, const unsigned short* __restrict__ wT,
    const float* __restrict__ att, unsigned short* __restrict__ h16,
    float* __restrict__ s_src, float* __restrict__ s_dst)
{
    __shared__ unsigned short x_lds[64 * 128];   // 16 KB
    const int tid = threadIdx.x;
    const int nbase = blockIdx.x * 64;

    #pragma unroll
    for (int s = 0; s < 8; ++s) {
        int i = s * 256 + tid;            // float4 unit 0..2047
        int node = i >> 5;                // 0..63
        int q = i & 31;                   // float4 within row
        float4 v = make_float4(0.f, 0.f, 0.f, 0.f);
        int gn = nbase + node;
        if (gn < N_NODES) v = ((const float4*)x)[(size_t)gn * 32 + q];
        ushort4 b;
        b.x = (unsigned short)f2bf(v.x);
        b.y = (unsigned short)f2bf(v.y);
        b.z = (unsigned short)f2bf(v.z);
        b.w = (unsigned short)f2bf(v.w);
        int chunk = q >> 1, half = q & 1;
        int sw = chunk ^ (node & 7);
        *(ushort4*)&x_lds[node * 128 + sw * 8 + half * 4] = b;
    }
    __syncthreads();

    const int wid = tid >> 6, lane = tid & 63;
    const int g = lane >> 4, m = lane & 15;
    const int rt = wid;

    float4v acc[4] = {{0.f,0.f,0.f,0.f},{0.f,0.f,0.f,0.f},
                      {0.f,0.f,0.f,0.f},{0.f,0.f,0.f,0.f}};
    #pragma unroll
    for (int kk = 0; kk < 4; ++kk) {
        int chunk = (kk * 4 + g) ^ (m & 7);
        short8v a = *(const short8v*)&x_lds[(rt * 16 + m) * 128 + chunk * 8];
        #pragma unroll
        for (int ct = 0; ct < 4; ++ct) {
            short8v bfr = *(const short8v*)&wT[(ct * 16 + m) * IN_CH + kk * 32 + g * 8];
            acc[ct] = __builtin_amdgcn_mfma_f32_16x16x32_bf16(a, bfr, acc[ct], 0, 0, 0);
        }
    }

    // h16 store + per-head attention scalar reduce
    #pragma unroll
    for (int ct = 0; ct < 4; ++ct) {
        float as = att[ct * 32 + m];
        float ad = att[ct * 32 + 16 + m];
        float ts[4], td[4];
        #pragma unroll
        for (int r = 0; r < 4; ++r) {
            int node = nbase + rt * 16 + g * 4 + r;
            float v = acc[ct][r];
            if (node < N_NODES)
                h16[(size_t)node * HC + ct * 16 + m] = (unsigned short)f2bf(v);
            ts[r] = v * as;
            td[r] = v * ad;
        }
        #pragma unroll
        for (int msk = 1; msk <= 8; msk <<= 1) {
            #pragma unroll
            for (int r = 0; r < 4; ++r) {
                ts[r] += __shfl_xor(ts[r], msk, 64);
                td[r] += __shfl_xor(td[r], msk, 64);
            }
        }
        if (m == 0) {
            #pragma unroll
            for (int r = 0; r < 4; ++r) {
                int node = nbase + rt * 16 + g * 4 + r;
                if (node < N_NODES) {
                    s_src[node * HEADS + ct] = ts[r];
                    s_dst[node * HEADS + ct] = td[r];
                }
            }
        }
    }
}

// ---------------- Kernel H: per-(block,bucket) histogram + eif ------------
__global__ __launch_bounds__(256) void histM_kernel(
    const int* __restrict__ ei, unsigned* __restrict__ M,
    float* __restrict__ eif)
{
    __shared__ unsigned lh[NBUCK];
    const int tid = threadIdx.x;
    for (int j = tid; j < NBUCK; j += 256) lh[j] = 0;
    __syncthreads();
    const int base = blockIdx.x * BIN_TILE;
    #pragma unroll
    for (int k = 0; k < 8; ++k) {
        int e = base + k * 256 + tid;
        if (e < N_EDGES) {
            unsigned r = (unsigned)ei[e];
            unsigned c = (unsigned)ei[N_EDGES + e];
            eif[e] = (float)r;
            eif[(size_t)E_FULL + e] = (float)c;
            atomicAdd(&lh[r / BUCKET_NODES], 1u);
        }
    }
    __syncthreads();
    unsigned* Mb = M + (size_t)blockIdx.x * NBUCK;
    for (int j = tid; j < NBUCK; j += 256) Mb[j] = lh[j];
}

// ---------------- Scan over flattened [bucket][block] counts ---------------
__device__ __forceinline__ unsigned block_excl_scan(unsigned v, unsigned* total,
                                                    int tid) {
    const int lane = tid & 63, wid = tid >> 6;
    unsigned x = v;
    #pragma unroll
    for (int d = 1; d < 64; d <<= 1) {
        unsigned t = __shfl_up(x, d, 64);
        if (lane >= d) x += t;
    }
    __shared__ unsigned wsum[4];
    if (lane == 63) wsum[wid] = x;
    __syncthreads();
    unsigned woff = 0;
    for (int i = 0; i < wid; ++i) woff += wsum[i];
    unsigned incl = x + woff;
    if (tid == 255) *total = incl;
    return incl - v;
}

__global__ __launch_bounds__(256) void scanA_kernel(
    const unsigned* __restrict__ M, unsigned* __restrict__ localx,
    unsigned* __restrict__ partials)
{
    const int tid = threadIdx.x;
    const int f = blockIdx.x * 256 + tid;   // flat = bucket*NBLK_BIN + block
    unsigned v = 0;
    if (f < T_FLAT) {
        int bucket = f / NBLK_BIN;
        int blk = f - bucket * NBLK_BIN;
        v = M[(size_t)blk * NBUCK + bucket];
    }
    __shared__ unsigned tot;
    unsigned excl = block_excl_scan(v, &tot, tid);
    if (f < T_FLAT) localx[f] = excl;
    __syncthreads();
    if (tid == 0) partials[blockIdx.x] = tot;
}

__global__ __launch_bounds__(256) void scanB_kernel(
    const unsigned* __restrict__ partials, unsigned* __restrict__ pscan)
{
    __shared__ unsigned tot_sh;
    __shared__ unsigned carry_sh;
    const int tid = threadIdx.x;
    if (tid == 0) carry_sh = 0;
    __syncthreads();
    const int nchunk = (SCANA_BLOCKS + 255) / 256;
    for (int ch = 0; ch < nchunk; ++ch) {
        int i = ch * 256 + tid;
        unsigned v = (i < SCANA_BLOCKS) ? partials[i] : 0u;
        unsigned excl = block_excl_scan(v, &tot_sh, tid);
        unsigned carry = carry_sh;
        if (i < SCANA_BLOCKS) pscan[i] = excl + carry;
        __syncthreads();
        if (tid == 0) carry_sh += tot_sh;
        __syncthreads();
    }
}

__global__ __launch_bounds__(256) void scanC_kernel(
    const unsigned* __restrict__ localx, const unsigned* __restrict__ pscan,
    unsigned* __restrict__ S)
{
    const int f = blockIdx.x * 256 + threadIdx.x;
    if (f < T_FLAT) S[f] = localx[f] + pscan[blockIdx.x];
    if (f == 0) S[T_FLAT] = N_EDGES;
}

// ---------------- Kernel D: bin pass — alpha + grouped slot writes --------
__global__ __launch_bounds__(256) void bin_kernel(
    const int* __restrict__ ei, const float* __restrict__ ea,
    const float* __restrict__ s_src, const float* __restrict__ s_dst,
    const unsigned* __restrict__ S, uint4* __restrict__ slots,
    float* __restrict__ alpha)
{
    __shared__ unsigned lh[NBUCK];
    __shared__ unsigned lbase[NBUCK];
    const int tid = threadIdx.x;
    for (int j = tid; j < NBUCK; j += 256) lh[j] = 0;
    __syncthreads();

    const int base = blockIdx.x * BIN_TILE;
    unsigned b8[8], idx8[8], p0[8], p1[8], p2[8];
    #pragma unroll
    for (int k = 0; k < 8; ++k) {
        int e = base + k * 256 + tid;
        b8[k] = 0xffffffffu;
        if (e < N_EDGES) {
            unsigned r = (unsigned)ei[e];
            unsigned c = (unsigned)ei[N_EDGES + e];
            float4 ss = ((const float4*)s_src)[r];
            float4 sd = ((const float4*)s_dst)[c];
            float4 eav = ((const float4*)ea)[e];
            float4 a;
            a.x = leaky(ss.x + sd.x) * eav.x;
            a.y = leaky(ss.y + sd.y) * eav.y;
            a.z = leaky(ss.z + sd.z) * eav.z;
            a.w = leaky(ss.w + sd.w) * eav.w;
            ((float4*)alpha)[e] = a;

            unsigned bk = r / BUCKET_NODES;
            unsigned rl = r - bk * BUCKET_NODES;
            b8[k] = bk;
            p0[k] = c | (rl << 16);
            p1[k] = f2bf(a.x) | (f2bf(a.y) << 16);
            p2[k] = f2bf(a.z) | (f2bf(a.w) << 16);
            idx8[k] = atomicAdd(&lh[bk], 1u);
        }
    }
    __syncthreads();
    for (int j = tid; j < NBUCK; j += 256)
        lbase[j] = S[(size_t)j * NBLK_BIN + blockIdx.x];
    __syncthreads();
    #pragma unroll
    for (int k = 0; k < 8; ++k) {
        if (b8[k] != 0xffffffffu)
            slots[lbase[b8[k]] + idx8[k]] = make_uint4(p0[k], p1[k], p2[k], 0u);
    }
}

// ---------------- Kernel S: per-bucket counting sort -> node-sorted slots --
__global__ __launch_bounds__(256) void sort_kernel(
    const unsigned* __restrict__ S, const uint4* __restrict__ slots,
    uint4* __restrict__ slots2, unsigned* __restrict__ offs)
{
    __shared__ unsigned cnt[BUCKET_NODES];
    __shared__ unsigned cur[BUCKET_NODES];
    const int b = blockIdx.x;
    const int tid = threadIdx.x;
    const unsigned start = S[(size_t)b * NBLK_BIN];
    const unsigned end   = S[(size_t)(b + 1) * NBLK_BIN];

    for (int j = tid; j < BUCKET_NODES; j += 256) cnt[j] = 0;
    __syncthreads();
    for (unsigned i = start + tid; i < end; i += 256)
        atomicAdd(&cnt[slots[i].x >> 16], 1u);
    __syncthreads();
    if (tid == 0) {
        unsigned run = 0;
        for (int j = 0; j < BUCKET_NODES; ++j) {
            unsigned c = cnt[j];
            cur[j] = run;
            run += c;
        }
    }
    __syncthreads();
    const int nstart = b * BUCKET_NODES;
    for (int j = tid; j < BUCKET_NODES; j += 256) {
        int n = nstart + j;
        if (n <= N_NODES) offs[n] = start + cur[j];
    }
    __syncthreads();
    for (unsigned i = start + tid; i < end; i += 256) {
        uint4 s = slots[i];
        unsigned rl = s.x >> 16;
        unsigned pos = start + atomicAdd(&cur[rl], 1u);
        slots2[pos] = s;
    }
}

// ---------------- Kernel E: per-node register gather (8-deep MLP) ---------
__device__ __forceinline__ float slot_alpha(uint4 s, int hd) {
    unsigned w = (hd & 2) ? s.z : s.y;
    return bf2f((hd & 1) ? (w >> 16) : (w & 0xffffu));
}

__global__ __launch_bounds__(256) void gather_kernel(
    const unsigned short* __restrict__ h16, const float* __restrict__ s_src,
    const float* __restrict__ s_dst, const float* __restrict__ bias,
    const unsigned* __restrict__ offs, const uint4* __restrict__ slots2,
    float* __restrict__ alpha, float* __restrict__ out, float* __restrict__ eif)
{
    const int tid = threadIdx.x;
    const int n = blockIdx.x * 4 + (tid >> 6);
    if (n >= N_NODES) return;
    const int lane = tid & 63, hd = lane >> 4;

    float s_self = s_src[n * HEADS + hd] + s_dst[n * HEADS + hd];
    float acc = bias[lane] + leaky(s_self) * bf2f(h16[(size_t)n * HC + lane]);

    const unsigned start = offs[n];
    const int cnt = (int)(offs[n + 1] - start);

    int i = 0;
    for (; i + 7 < cnt; i += 8) {
        uint4 sl[8];
        float hv[8];
        #pragma unroll
        for (int u = 0; u < 8; ++u) sl[u] = slots2[start + i + u];
        #pragma unroll
        for (int u = 0; u < 8; ++u)
            hv[u] = bf2f(h16[(size_t)(sl[u].x & 0xffffu) * HC + lane]);
        #pragma unroll
        for (int u = 0; u < 8; ++u)
            acc = fmaf(slot_alpha(sl[u], hd), hv[u], acc);
    }
    for (; i < cnt; ++i) {
        uint4 s0 = slots2[start + i];
        float h0 = bf2f(h16[(size_t)(s0.x & 0xffffu) * HC + lane]);
        acc = fmaf(slot_alpha(s0, hd), h0, acc);
    }
    out[(size_t)n * HC + lane] = acc;

    if (lane < HEADS) {
        float s2 = s_src[n * HEADS + lane] + s_dst[n * HEADS + lane];
        alpha[(size_t)(N_EDGES + n) * HEADS + lane] = leaky(s2);
    }
    if (lane == 4) eif[N_EDGES + n] = (float)n;
    if (lane == 5) eif[(size_t)E_FULL + N_EDGES + n] = (float)n;
}

extern "C" void kernel_launch(void* const* d_in, const int* in_sizes, int n_in,
                              void* d_out, int out_size, void* d_ws, size_t ws_size,
                              hipStream_t stream) {
    const float* x      = (const float*)d_in[0];
    const int*   ei     = (const int*)  d_in[1];
    const float* ea     = (const float*)d_in[2];
    const float* weight = (const float*)d_in[3];
    const float* att    = (const float*)d_in[4];
    const float* bias   = (const float*)d_in[5];

    float* out   = (float*)d_out;                    // N_NODES*HC
    float* eif   = out + (size_t)N_NODES * HC;       // 2*E_FULL (as float)
    float* alpha = eif + (size_t)2 * E_FULL;         // E_FULL*HEADS

    // workspace layout (uint4 arrays first for 16B alignment); ~64.3 MB total
    uint4* slots  = (uint4*)d_ws;                                      // 25.6 MB
    uint4* slots2 = slots + (size_t)N_EDGES;                           // 25.6 MB
    unsigned short* wT = (unsigned short*)(slots2 + (size_t)N_EDGES);  // 16 KB (16B-aligned)
    unsigned short* h16 = wT + (size_t)IN_CH * HC;                     // 6.4 MB
    float* s_src = (float*)(h16 + (size_t)N_NODES * HC);               // 0.8 MB
    float* s_dst = s_src + (size_t)N_NODES * HEADS;                    // 0.8 MB
    unsigned* M        = (unsigned*)(s_dst + (size_t)N_NODES * HEADS); // 1.6 MB
    unsigned* localx   = M + (size_t)NBLK_BIN * NBUCK;                 // 1.6 MB
    unsigned* partials = localx + T_FLAT;                              // 6 KB
    unsigned* pscan    = partials + SCANA_BLOCKS;                      // 6 KB
    unsigned* S        = pscan + SCANA_BLOCKS;                         // 1.6 MB (T_FLAT+1)
    unsigned* offs     = S + (T_FLAT + 1);                             // 0.2 MB (N_NODES+1)

    wcvt_kernel<<<(IN_CH * HC + 255) / 256, 256, 0, stream>>>(weight, wT);
    gemm_h_kernel<<<(N_NODES + 63) / 64, 256, 0, stream>>>(x, wT, att, h16, s_src, s_dst);
    histM_kernel<<<NBLK_BIN, 256, 0, stream>>>(ei, M, eif);
    scanA_kernel<<<SCANA_BLOCKS, 256, 0, stream>>>(M, localx, partials);
    scanB_kernel<<<1, 256, 0, stream>>>(partials, pscan);
    scanC_kernel<<<SCANA_BLOCKS, 256, 0, stream>>>(localx, pscan, S);
    bin_kernel<<<NBLK_BIN, 256, 0, stream>>>(ei, ea, s_src, s_dst, S, slots, alpha);
    sort_kernel<<<NBUCK, 256, 0, stream>>>(S, slots, slots2, offs);
    gather_kernel<<<(N_NODES + 3) / 4, 256, 0, stream>>>(
        h16, s_src, s_dst, bias, offs, slots2, alpha, out, eif);
}